// Round 1
// baseline (1879.612 us; speedup 1.0000x reference)
//
#include <hip/hip_runtime.h>

#define NROWS 65536
#define FEA   512
#define MEM   2000
#define LAMBDA 0.0025f
#define EPS    1e-12f

// ------------------------------------------------------------------
// Kernel 1: S = x @ W^T   (fp32, 128x128 tile, BK=32, 256 threads)
// Writes raw scores into the att region of d_out (same size as att).
// ------------------------------------------------------------------
#define BK 32

__global__ __launch_bounds__(256) void gemm_scores(
    const float* __restrict__ x, const float* __restrict__ Wt,
    float* __restrict__ S) {
  __shared__ float xs[BK][129];   // transposed: xs[k][row], +1 pad
  __shared__ float ws[BK][129];   // transposed: ws[k][col], +1 pad

  const int tid = threadIdx.x;
  const int rm0 = blockIdx.x * 128;
  const int cn0 = blockIdx.y * 128;
  const int tx = tid & 15;        // col group
  const int ty = tid >> 4;        // row group
  const int sr = tid >> 3;        // staging row 0..31
  const int kq = tid & 7;         // staging k-quad 0..7

  float acc[8][8];
#pragma unroll
  for (int i = 0; i < 8; ++i)
#pragma unroll
    for (int j = 0; j < 8; ++j) acc[i][j] = 0.f;

  for (int k0 = 0; k0 < FEA; k0 += BK) {
    // ---- stage A and B tiles (coalesced float4 global, transposed LDS) ----
#pragma unroll
    for (int b = 0; b < 4; ++b) {
      const int row = sr + 32 * b;  // 0..127
      float4 v = *(const float4*)(x + (size_t)(rm0 + row) * FEA + k0 + kq * 4);
      xs[kq * 4 + 0][row] = v.x; xs[kq * 4 + 1][row] = v.y;
      xs[kq * 4 + 2][row] = v.z; xs[kq * 4 + 3][row] = v.w;
      int wr = cn0 + row; wr = (wr < MEM) ? wr : (MEM - 1);  // clamp OOB cols
      float4 u = *(const float4*)(Wt + (size_t)wr * FEA + k0 + kq * 4);
      ws[kq * 4 + 0][row] = u.x; ws[kq * 4 + 1][row] = u.y;
      ws[kq * 4 + 2][row] = u.z; ws[kq * 4 + 3][row] = u.w;
    }
    __syncthreads();

#pragma unroll 8
    for (int k = 0; k < BK; ++k) {
      float a[8], bb[8];
      float4 t0 = *(const float4*)&xs[k][4 * ty];
      float4 t1 = *(const float4*)&xs[k][64 + 4 * ty];
      a[0] = t0.x; a[1] = t0.y; a[2] = t0.z; a[3] = t0.w;
      a[4] = t1.x; a[5] = t1.y; a[6] = t1.z; a[7] = t1.w;
      float4 u0 = *(const float4*)&ws[k][4 * tx];
      float4 u1 = *(const float4*)&ws[k][64 + 4 * tx];
      bb[0] = u0.x; bb[1] = u0.y; bb[2] = u0.z; bb[3] = u0.w;
      bb[4] = u1.x; bb[5] = u1.y; bb[6] = u1.z; bb[7] = u1.w;
#pragma unroll
      for (int i = 0; i < 8; ++i)
#pragma unroll
        for (int j = 0; j < 8; ++j)
          acc[i][j] = fmaf(a[i], bb[j], acc[i][j]);
    }
    __syncthreads();
  }

  // ---- store scores (float4, col-guarded; 2000 % 4 == 0 so no partial quads)
#pragma unroll
  for (int i = 0; i < 8; ++i) {
    const int row = rm0 + ((i < 4) ? (4 * ty + i) : (64 + 4 * ty + (i - 4)));
    const int c0 = cn0 + 4 * tx;
    const int c1 = cn0 + 64 + 4 * tx;
    if (c0 < MEM) {
      float4 v; v.x = acc[i][0]; v.y = acc[i][1]; v.z = acc[i][2]; v.w = acc[i][3];
      *(float4*)(S + (size_t)row * MEM + c0) = v;
    }
    if (c1 < MEM) {
      float4 v; v.x = acc[i][4]; v.y = acc[i][5]; v.z = acc[i][6]; v.w = acc[i][7];
      *(float4*)(S + (size_t)row * MEM + c1) = v;
    }
  }
}

// ------------------------------------------------------------------
// Kernel 2: per 8-row block: softmax -> hard_shrink_relu -> renorm,
// write att, and sparse out = att @ W via ballot over nonzeros.
// One wave per row (512 threads = 8 waves).
// ------------------------------------------------------------------
__global__ __launch_bounds__(512) void softmax_shrink_out(
    const float* __restrict__ Wt, float* __restrict__ out,
    float* __restrict__ att /* holds raw scores on entry */) {
  __shared__ float sl[8 * MEM];

  const int tid = threadIdx.x;
  const int r0 = blockIdx.x * 8;

  // ---- stage 8 rows of scores (contiguous 16000 floats) ----
  {
    const float* Sblk = att + (size_t)r0 * MEM;
#pragma unroll
    for (int jj = 0; jj < 8; ++jj) {
      int q = tid + 512 * jj;        // quad index
      if (q < (8 * MEM) / 4) {
        float4 v = *(const float4*)(Sblk + 4 * q);
        *(float4*)&sl[4 * q] = v;
      }
    }
  }
  __syncthreads();

  const int w = tid >> 6;   // wave id = local row 0..7
  const int l = tid & 63;   // lane
  float* row_lds = &sl[w * MEM];
  const int grow = r0 + w;

  // ---- row max ----
  float m = -INFINITY;
  for (int j = 0; j < 32; ++j) {
    int c = l + 64 * j;
    if (c < MEM) m = fmaxf(m, row_lds[c]);
  }
#pragma unroll
  for (int off = 32; off; off >>= 1) m = fmaxf(m, __shfl_xor(m, off));

  // ---- exp + sum ----
  float s = 0.f;
  for (int j = 0; j < 32; ++j) {
    int c = l + 64 * j;
    if (c < MEM) {
      float e = expf(row_lds[c] - m);
      row_lds[c] = e;
      s += e;
    }
  }
#pragma unroll
  for (int off = 32; off; off >>= 1) s += __shfl_xor(s, off);

  // ---- softmax divide + hard shrink, accumulate shrink-sum ----
  float qs = 0.f;
  for (int j = 0; j < 32; ++j) {
    int c = l + 64 * j;
    if (c < MEM) {
      float p = row_lds[c] / s;                 // softmax prob
      float d = p - LAMBDA;
      float q = fmaxf(d, 0.f) * p / (fabsf(d) + EPS);  // literal formula
      row_lds[c] = q;
      qs += q;
    }
  }
#pragma unroll
  for (int off = 32; off; off >>= 1) qs += __shfl_xor(qs, off);
  const float denom = fmaxf(qs, EPS);

  // ---- finalize att, write it, and accumulate sparse out ----
  float4 oa0 = {0.f, 0.f, 0.f, 0.f};
  float4 oa1 = {0.f, 0.f, 0.f, 0.f};
  for (int j = 0; j < 32; ++j) {
    int c = l + 64 * j;
    float a = 0.f;
    if (c < MEM) {
      a = row_lds[c] / denom;
      att[(size_t)grow * MEM + c] = a;
    }
    unsigned long long msk = __ballot(a > 0.f);
    while (msk) {
      int b = __ffsll(msk) - 1;
      msk &= msk - 1;
      float av = __shfl(a, b);
      int cc = b + 64 * j;
      const float* wp = Wt + (size_t)cc * FEA;
      float4 w0 = *(const float4*)(wp + 4 * l);
      float4 w1 = *(const float4*)(wp + 256 + 4 * l);
      oa0.x = fmaf(av, w0.x, oa0.x); oa0.y = fmaf(av, w0.y, oa0.y);
      oa0.z = fmaf(av, w0.z, oa0.z); oa0.w = fmaf(av, w0.w, oa0.w);
      oa1.x = fmaf(av, w1.x, oa1.x); oa1.y = fmaf(av, w1.y, oa1.y);
      oa1.z = fmaf(av, w1.z, oa1.z); oa1.w = fmaf(av, w1.w, oa1.w);
    }
  }

  float* op = out + (size_t)grow * FEA;
  *(float4*)(op + 4 * l) = oa0;
  *(float4*)(op + 256 + 4 * l) = oa1;
}

// ------------------------------------------------------------------
extern "C" void kernel_launch(void* const* d_in, const int* in_sizes, int n_in,
                              void* d_out, int out_size, void* d_ws, size_t ws_size,
                              hipStream_t stream) {
  (void)in_sizes; (void)n_in; (void)d_ws; (void)ws_size; (void)out_size;
  const float* x = (const float*)d_in[0];
  const float* W = (const float*)d_in[1];
  float* out = (float*)d_out;
  float* att = (float*)d_out + (size_t)NROWS * FEA;  // scores live here between k1/k2

  dim3 g1(NROWS / 128, (MEM + 127) / 128);  // 512 x 16
  gemm_scores<<<g1, 256, 0, stream>>>(x, W, att);
  softmax_shrink_out<<<NROWS / 8, 512, 0, stream>>>(W, out, att);
}

// Round 2
// 832.342 us; speedup vs baseline: 2.2582x; 2.2582x over previous
//
#include <hip/hip_runtime.h>

#define NROWS 65536
#define FEA   512
#define MEM   2000
#define MEMP  2048
#define LAMBDA 0.0025f
#define EPS    1e-12f

#define PLX ((long)NROWS * FEA)   // elements per x plane
#define PLW ((long)MEMP * FEA)    // elements per W plane
#define GBK 32                    // K per LDS tile

typedef unsigned short ushort_t;
typedef __attribute__((ext_vector_type(8))) short bf16x8;
typedef __attribute__((ext_vector_type(16))) float f32x16;

// ---------- bf16 split helpers (RNE) ----------
__device__ inline ushort_t f2bf(float f) {
  unsigned int u = __float_as_uint(f);
  unsigned int r = (u + 0x7FFFu + ((u >> 16) & 1u)) >> 16;
  return (ushort_t)r;
}
__device__ inline float bf2f(ushort_t h) {
  return __uint_as_float(((unsigned int)h) << 16);
}

__device__ inline void gload_lds16(const void* g, void* l) {
  __builtin_amdgcn_global_load_lds(
      (const __attribute__((address_space(1))) unsigned int*)g,
      (__attribute__((address_space(3))) unsigned int*)l, 16, 0, 0);
}

// ------------------------------------------------------------------
// K0a: split x (fp32) -> xh, xl bf16 planes (stored in out region)
// ------------------------------------------------------------------
__global__ __launch_bounds__(256) void split_x(const float* __restrict__ x,
                                               ushort_t* __restrict__ xpl) {
  const long n4 = PLX / 4;
  long i = (long)blockIdx.x * 256 + threadIdx.x;
  const long stride = (long)gridDim.x * 256;
  for (; i < n4; i += stride) {
    float4 v = ((const float4*)x)[i];
    float f[4] = {v.x, v.y, v.z, v.w};
    ushort_t hh[4], ll[4];
#pragma unroll
    for (int j = 0; j < 4; ++j) {
      hh[j] = f2bf(f[j]);
      ll[j] = f2bf(f[j] - bf2f(hh[j]));
    }
    ushort4 h; h.x = hh[0]; h.y = hh[1]; h.z = hh[2]; h.w = hh[3];
    ushort4 l; l.x = ll[0]; l.y = ll[1]; l.z = ll[2]; l.w = ll[3];
    ((ushort4*)xpl)[i] = h;
    ((ushort4*)(xpl + PLX))[i] = l;
  }
}

// ------------------------------------------------------------------
// K0b: split W -> wh, wl planes, padded to 2048 rows (zeros)
// ------------------------------------------------------------------
__global__ __launch_bounds__(256) void split_w(const float* __restrict__ W,
                                               ushort_t* __restrict__ wpl) {
  long i = (long)blockIdx.x * 256 + threadIdx.x;  // quad index over padded plane
  if (i >= PLW / 4) return;
  long row = i / (FEA / 4);
  ushort4 h = {0, 0, 0, 0}, l = {0, 0, 0, 0};
  if (row < MEM) {
    float4 v = ((const float4*)W)[i];
    float f[4] = {v.x, v.y, v.z, v.w};
    ushort_t hh[4], ll[4];
#pragma unroll
    for (int j = 0; j < 4; ++j) {
      hh[j] = f2bf(f[j]);
      ll[j] = f2bf(f[j] - bf2f(hh[j]));
    }
    h.x = hh[0]; h.y = hh[1]; h.z = hh[2]; h.w = hh[3];
    l.x = ll[0]; l.y = ll[1]; l.z = ll[2]; l.w = ll[3];
  }
  ((ushort4*)wpl)[i] = h;
  ((ushort4*)(wpl + PLW))[i] = l;
}

// ------------------------------------------------------------------
// K1: S = x @ W^T via split-bf16 MFMA (3 products, 32x32x16)
// 128x128 tile, BK=32, dbuf LDS, global_load_lds(16), XOR swizzle.
// LDS row layout: [row 0..127][plane 0..1][32 bf16] = 128 B/row,
// 8 chunks of 16 B; phys_chunk = logical_chunk ^ (row & 7).
// ------------------------------------------------------------------
__global__ __launch_bounds__(256, 2) void gemm_mfma(
    const ushort_t* __restrict__ xpl, const ushort_t* __restrict__ wpl,
    float* __restrict__ S) {
  __shared__ alignas(16) ushort_t lds[2][16384];  // [buf][A 8192 | B 8192]

  const int tid = threadIdx.x;
  const int wid = tid >> 6, lane = tid & 63;
  const int l32 = lane & 31, lh = lane >> 5;
  const int wr = wid >> 1, wc = wid & 1;

  // XCD-chunked bijective swizzle (8192 blocks, 8 XCDs):
  // round-robin dispatch -> each XCD gets a contiguous run of linear ids,
  // so all 16 N-tiles of an M-tile hit the same XCD's L2 (A-tile reuse).
  int wg = blockIdx.x;
  int lin = ((wg & 7) << 10) + (wg >> 3);
  const int mt = lin >> 4, nt = lin & 15;
  const long rm0 = (long)mt * 128;
  const int cn0 = nt * 128;

  f32x16 acc[2][2] = {};

  auto stage = [&](int buf, int kt) {
    const int k0 = kt * GBK;
#pragma unroll
    for (int i = 0; i < 4; ++i) {  // A tile: 1024 chunks of 16 B
      int id = i * 256 + tid;
      int row = id >> 3;
      int lc = (id & 7) ^ (row & 7);  // inverse-swizzled logical chunk
      long goff = (long)(lc >> 2) * PLX + (rm0 + row) * FEA + k0 + (lc & 3) * 8;
      gload_lds16(xpl + goff, &lds[buf][id * 8]);
    }
#pragma unroll
    for (int i = 0; i < 4; ++i) {  // B tile
      int id = i * 256 + tid;
      int row = id >> 3;
      int lc = (id & 7) ^ (row & 7);
      long goff = (long)(lc >> 2) * PLW + (long)(cn0 + row) * FEA + k0 + (lc & 3) * 8;
      gload_lds16(wpl + goff, &lds[buf][8192 + id * 8]);
    }
  };

  auto compute = [&](int buf) {
    const ushort_t* A = &lds[buf][0];
    const ushort_t* B = &lds[buf][8192];
#pragma unroll
    for (int s = 0; s < 2; ++s) {  // two K=16 steps per BK=32 tile
      bf16x8 ah[2], al[2], bh[2], bl[2];
#pragma unroll
      for (int m = 0; m < 2; ++m) {
        int row = wr * 64 + m * 32 + l32;
        int r7 = row & 7;
        ah[m] = *(const bf16x8*)(A + row * 64 + (((s * 2 + lh) ^ r7) * 8));
        al[m] = *(const bf16x8*)(A + row * 64 + (((4 + s * 2 + lh) ^ r7) * 8));
      }
#pragma unroll
      for (int n = 0; n < 2; ++n) {
        int row = wc * 64 + n * 32 + l32;
        int r7 = row & 7;
        bh[n] = *(const bf16x8*)(B + row * 64 + (((s * 2 + lh) ^ r7) * 8));
        bl[n] = *(const bf16x8*)(B + row * 64 + (((4 + s * 2 + lh) ^ r7) * 8));
      }
#pragma unroll
      for (int m = 0; m < 2; ++m)
#pragma unroll
        for (int n = 0; n < 2; ++n) {
          acc[m][n] = __builtin_amdgcn_mfma_f32_32x32x16_bf16(ah[m], bh[n], acc[m][n], 0, 0, 0);
          acc[m][n] = __builtin_amdgcn_mfma_f32_32x32x16_bf16(ah[m], bl[n], acc[m][n], 0, 0, 0);
          acc[m][n] = __builtin_amdgcn_mfma_f32_32x32x16_bf16(al[m], bh[n], acc[m][n], 0, 0, 0);
        }
    }
  };

  stage(0, 0);
#pragma unroll 2
  for (int kt = 0; kt < FEA / GBK; ++kt) {
    __syncthreads();                       // drains vmcnt (stage done) + prior reads
    if (kt < FEA / GBK - 1) stage((kt + 1) & 1, kt + 1);  // prefetch overlaps MFMA
    compute(kt & 1);
  }

  // epilogue: C/D layout col=lane&31, row=(reg&3)+8*(reg>>2)+4*(lane>>5)
#pragma unroll
  for (int m = 0; m < 2; ++m)
#pragma unroll
    for (int n = 0; n < 2; ++n) {
      int col = cn0 + wc * 64 + n * 32 + l32;
      if (col < MEM) {
        long rbase = rm0 + wr * 64 + m * 32 + 4 * lh;
#pragma unroll
        for (int r = 0; r < 16; ++r) {
          long row = rbase + (r & 3) + 8 * (r >> 2);
          S[row * MEM + col] = acc[m][n][r];
        }
      }
    }
}

// ------------------------------------------------------------------
// Fallback fp32 GEMM (round-1, used only if ws too small)
// ------------------------------------------------------------------
#define BK 32
__global__ __launch_bounds__(256) void gemm_scores(
    const float* __restrict__ x, const float* __restrict__ Wt,
    float* __restrict__ S) {
  __shared__ float xs[BK][129];
  __shared__ float ws[BK][129];
  const int tid = threadIdx.x;
  const int rm0 = blockIdx.x * 128;
  const int cn0 = blockIdx.y * 128;
  const int tx = tid & 15, ty = tid >> 4;
  const int sr = tid >> 3, kq = tid & 7;
  float acc[8][8];
#pragma unroll
  for (int i = 0; i < 8; ++i)
#pragma unroll
    for (int j = 0; j < 8; ++j) acc[i][j] = 0.f;
  for (int k0 = 0; k0 < FEA; k0 += BK) {
#pragma unroll
    for (int b = 0; b < 4; ++b) {
      const int row = sr + 32 * b;
      float4 v = *(const float4*)(x + (size_t)(rm0 + row) * FEA + k0 + kq * 4);
      xs[kq * 4 + 0][row] = v.x; xs[kq * 4 + 1][row] = v.y;
      xs[kq * 4 + 2][row] = v.z; xs[kq * 4 + 3][row] = v.w;
      int wr = cn0 + row; wr = (wr < MEM) ? wr : (MEM - 1);
      float4 u = *(const float4*)(Wt + (size_t)wr * FEA + k0 + kq * 4);
      ws[kq * 4 + 0][row] = u.x; ws[kq * 4 + 1][row] = u.y;
      ws[kq * 4 + 2][row] = u.z; ws[kq * 4 + 3][row] = u.w;
    }
    __syncthreads();
#pragma unroll 8
    for (int k = 0; k < BK; ++k) {
      float a[8], bb[8];
      float4 t0 = *(const float4*)&xs[k][4 * ty];
      float4 t1 = *(const float4*)&xs[k][64 + 4 * ty];
      a[0] = t0.x; a[1] = t0.y; a[2] = t0.z; a[3] = t0.w;
      a[4] = t1.x; a[5] = t1.y; a[6] = t1.z; a[7] = t1.w;
      float4 u0 = *(const float4*)&ws[k][4 * tx];
      float4 u1 = *(const float4*)&ws[k][64 + 4 * tx];
      bb[0] = u0.x; bb[1] = u0.y; bb[2] = u0.z; bb[3] = u0.w;
      bb[4] = u1.x; bb[5] = u1.y; bb[6] = u1.z; bb[7] = u1.w;
#pragma unroll
      for (int i = 0; i < 8; ++i)
#pragma unroll
        for (int j = 0; j < 8; ++j)
          acc[i][j] = fmaf(a[i], bb[j], acc[i][j]);
    }
    __syncthreads();
  }
#pragma unroll
  for (int i = 0; i < 8; ++i) {
    const int row = rm0 + ((i < 4) ? (4 * ty + i) : (64 + 4 * ty + (i - 4)));
    const int c0 = cn0 + 4 * tx;
    const int c1 = cn0 + 64 + 4 * tx;
    if (c0 < MEM) {
      float4 v; v.x = acc[i][0]; v.y = acc[i][1]; v.z = acc[i][2]; v.w = acc[i][3];
      *(float4*)(S + (size_t)row * MEM + c0) = v;
    }
    if (c1 < MEM) {
      float4 v; v.x = acc[i][4]; v.y = acc[i][5]; v.z = acc[i][6]; v.w = acc[i][7];
      *(float4*)(S + (size_t)row * MEM + c1) = v;
    }
  }
}

// ------------------------------------------------------------------
// K2: softmax -> hard shrink -> renorm -> write att + sparse out
// ------------------------------------------------------------------
__global__ __launch_bounds__(512) void softmax_shrink_out(
    const float* __restrict__ Wt, float* __restrict__ out,
    float* __restrict__ att /* raw scores on entry */) {
  __shared__ float sl[8 * MEM];
  const int tid = threadIdx.x;
  const int r0 = blockIdx.x * 8;
  {
    const float* Sblk = att + (size_t)r0 * MEM;
#pragma unroll
    for (int jj = 0; jj < 8; ++jj) {
      int q = tid + 512 * jj;
      if (q < (8 * MEM) / 4) {
        float4 v = *(const float4*)(Sblk + 4 * q);
        *(float4*)&sl[4 * q] = v;
      }
    }
  }
  __syncthreads();
  const int w = tid >> 6;
  const int l = tid & 63;
  float* row_lds = &sl[w * MEM];
  const int grow = r0 + w;

  float m = -INFINITY;
  for (int j = 0; j < 32; ++j) {
    int c = l + 64 * j;
    if (c < MEM) m = fmaxf(m, row_lds[c]);
  }
#pragma unroll
  for (int off = 32; off; off >>= 1) m = fmaxf(m, __shfl_xor(m, off));

  float s = 0.f;
  for (int j = 0; j < 32; ++j) {
    int c = l + 64 * j;
    if (c < MEM) {
      float e = expf(row_lds[c] - m);
      row_lds[c] = e;
      s += e;
    }
  }
#pragma unroll
  for (int off = 32; off; off >>= 1) s += __shfl_xor(s, off);

  float qs = 0.f;
  for (int j = 0; j < 32; ++j) {
    int c = l + 64 * j;
    if (c < MEM) {
      float p = row_lds[c] / s;
      float d = p - LAMBDA;
      float q = fmaxf(d, 0.f) * p / (fabsf(d) + EPS);
      row_lds[c] = q;
      qs += q;
    }
  }
#pragma unroll
  for (int off = 32; off; off >>= 1) qs += __shfl_xor(qs, off);
  const float denom = fmaxf(qs, EPS);

  float4 oa0 = {0.f, 0.f, 0.f, 0.f};
  float4 oa1 = {0.f, 0.f, 0.f, 0.f};
  for (int j = 0; j < 32; ++j) {
    int c = l + 64 * j;
    float a = 0.f;
    if (c < MEM) {
      a = row_lds[c] / denom;
      att[(size_t)grow * MEM + c] = a;
    }
    unsigned long long msk = __ballot(a > 0.f);
    while (msk) {
      int b = __ffsll(msk) - 1;
      msk &= msk - 1;
      float av = __shfl(a, b);
      int cc = b + 64 * j;
      const float* wp = Wt + (size_t)cc * FEA;
      float4 w0 = *(const float4*)(wp + 4 * l);
      float4 w1 = *(const float4*)(wp + 256 + 4 * l);
      oa0.x = fmaf(av, w0.x, oa0.x); oa0.y = fmaf(av, w0.y, oa0.y);
      oa0.z = fmaf(av, w0.z, oa0.z); oa0.w = fmaf(av, w0.w, oa0.w);
      oa1.x = fmaf(av, w1.x, oa1.x); oa1.y = fmaf(av, w1.y, oa1.y);
      oa1.z = fmaf(av, w1.z, oa1.z); oa1.w = fmaf(av, w1.w, oa1.w);
    }
  }
  float* op = out + (size_t)grow * FEA;
  *(float4*)(op + 4 * l) = oa0;
  *(float4*)(op + 256 + 4 * l) = oa1;
}

// ------------------------------------------------------------------
extern "C" void kernel_launch(void* const* d_in, const int* in_sizes, int n_in,
                              void* d_out, int out_size, void* d_ws, size_t ws_size,
                              hipStream_t stream) {
  (void)in_sizes; (void)n_in; (void)out_size;
  const float* x = (const float*)d_in[0];
  const float* W = (const float*)d_in[1];
  float* out = (float*)d_out;
  float* att = (float*)d_out + (size_t)NROWS * FEA;

  const size_t w_need = (size_t)PLW * 2 * sizeof(ushort_t);  // 4 MB
  if (ws_size >= w_need) {
    ushort_t* xpl = (ushort_t*)d_out;  // out region: exactly fits 2 x-planes
    ushort_t* wpl = (ushort_t*)d_ws;
    split_x<<<2048, 256, 0, stream>>>(x, xpl);
    split_w<<<(int)(PLW / 4 / 256), 256, 0, stream>>>(W, wpl);
    gemm_mfma<<<8192, 256, 0, stream>>>(xpl, wpl, att);
  } else {
    dim3 g1(NROWS / 128, (MEM + 127) / 128);
    gemm_scores<<<g1, 256, 0, stream>>>(x, W, att);
  }
  softmax_shrink_out<<<NROWS / 8, 512, 0, stream>>>(W, out, att);
}

// Round 3
// 790.763 us; speedup vs baseline: 2.3770x; 1.0526x over previous
//
#include <hip/hip_runtime.h>

#define NROWS 65536
#define FEA   512
#define MEM   2000
#define MEMP  2048
#define LAMBDA 0.0025f
#define EPS    1e-12f

#define PLX ((long)NROWS * FEA)   // elements per x plane
#define PLW ((long)MEMP * FEA)    // elements per W plane

typedef unsigned short ushort_t;
typedef __attribute__((ext_vector_type(8))) short bf16x8;
typedef __attribute__((ext_vector_type(16))) float f32x16;

// ---------- bf16 split helpers (RNE) ----------
__device__ inline ushort_t f2bf(float f) {
  unsigned int u = __float_as_uint(f);
  unsigned int r = (u + 0x7FFFu + ((u >> 16) & 1u)) >> 16;
  return (ushort_t)r;
}
__device__ inline float bf2f(ushort_t h) {
  return __uint_as_float(((unsigned int)h) << 16);
}

__device__ inline void gload_lds16(const void* g, void* l) {
  __builtin_amdgcn_global_load_lds(
      (const __attribute__((address_space(1))) unsigned int*)g,
      (__attribute__((address_space(3))) unsigned int*)l, 16, 0, 0);
}

// ------------------------------------------------------------------
// K0a: split x (fp32) -> xh, xl bf16 planes (stored in out region)
// ------------------------------------------------------------------
__global__ __launch_bounds__(256) void split_x(const float* __restrict__ x,
                                               ushort_t* __restrict__ xpl) {
  const long n4 = PLX / 4;
  long i = (long)blockIdx.x * 256 + threadIdx.x;
  const long stride = (long)gridDim.x * 256;
  for (; i < n4; i += stride) {
    float4 v = ((const float4*)x)[i];
    float f[4] = {v.x, v.y, v.z, v.w};
    ushort_t hh[4], ll[4];
#pragma unroll
    for (int j = 0; j < 4; ++j) {
      hh[j] = f2bf(f[j]);
      ll[j] = f2bf(f[j] - bf2f(hh[j]));
    }
    ushort4 h; h.x = hh[0]; h.y = hh[1]; h.z = hh[2]; h.w = hh[3];
    ushort4 l; l.x = ll[0]; l.y = ll[1]; l.z = ll[2]; l.w = ll[3];
    ((ushort4*)xpl)[i] = h;
    ((ushort4*)(xpl + PLX))[i] = l;
  }
}

// ------------------------------------------------------------------
// K0b: split W -> wh, wl planes, padded to 2048 rows (zeros)
// ------------------------------------------------------------------
__global__ __launch_bounds__(256) void split_w(const float* __restrict__ W,
                                               ushort_t* __restrict__ wpl) {
  long i = (long)blockIdx.x * 256 + threadIdx.x;
  if (i >= PLW / 4) return;
  long row = i / (FEA / 4);
  ushort4 h = {0, 0, 0, 0}, l = {0, 0, 0, 0};
  if (row < MEM) {
    float4 v = ((const float4*)W)[i];
    float f[4] = {v.x, v.y, v.z, v.w};
    ushort_t hh[4], ll[4];
#pragma unroll
    for (int j = 0; j < 4; ++j) {
      hh[j] = f2bf(f[j]);
      ll[j] = f2bf(f[j] - bf2f(hh[j]));
    }
    h.x = hh[0]; h.y = hh[1]; h.z = hh[2]; h.w = hh[3];
    l.x = ll[0]; l.y = ll[1]; l.z = ll[2]; l.w = ll[3];
  }
  ((ushort4*)wpl)[i] = h;
  ((ushort4*)(wpl + PLW))[i] = l;
}

// ------------------------------------------------------------------
// K1: S = x @ W^T, split-bf16 (3 products), 256x256 tile, BK=32.
// Deep pipeline: ring of 4 k-half slots/operand, counted vmcnt(8),
// 1 barrier per region, setprio around MFMA cluster.
// Slot: [256 rows][2 planes][16 k] bf16 = 64 B/row = 16 KB.
// Chunk swizzle: phys = c ^ ((row>>1)&3), c = plane*2 + k-octet.
// ------------------------------------------------------------------
__device__ __forceinline__ void stage_pair(
    int j, int tid, const ushort_t* __restrict__ xpl,
    const ushort_t* __restrict__ wpl, long rm0, int cn0,
    ushort_t* ldsA, ushort_t* ldsB) {
  ushort_t* dA = ldsA + (size_t)(j & 3) * 8192;
#pragma unroll
  for (int i = 0; i < 2; ++i) {
    int id = i * 512 + tid;
    int row = id >> 2;
    int c = (id & 3) ^ ((row >> 1) & 3);     // inverse-swizzled logical chunk
    long goff = (long)(c >> 1) * PLX + (rm0 + row) * FEA + j * 16 + (c & 1) * 8;
    gload_lds16(xpl + goff, dA + id * 8);    // linear LDS dest
  }
  ushort_t* dB = ldsB + (size_t)(j & 3) * 8192;
#pragma unroll
  for (int i = 0; i < 2; ++i) {
    int id = i * 512 + tid;
    int row = id >> 2;
    int c = (id & 3) ^ ((row >> 1) & 3);
    long goff = (long)(c >> 1) * PLW + (long)(cn0 + row) * FEA + j * 16 + (c & 1) * 8;
    gload_lds16(wpl + goff, dB + id * 8);
  }
}

template <int VM, bool ISSUE>
__device__ __forceinline__ void region_step(
    int R, int tid, int l32, int lh, int wm, int wn,
    const ushort_t* __restrict__ xpl, const ushort_t* __restrict__ wpl,
    long rm0, int cn0, ushort_t* ldsA, ushort_t* ldsB, f32x16 (&acc)[4][2]) {
  if constexpr (VM == 8)      asm volatile("s_waitcnt vmcnt(8)" ::: "memory");
  else if constexpr (VM == 4) asm volatile("s_waitcnt vmcnt(4)" ::: "memory");
  else                        asm volatile("s_waitcnt vmcnt(0)" ::: "memory");
  asm volatile("s_barrier" ::: "memory");

  const ushort_t* As = ldsA + (size_t)(R & 3) * 8192;
  const ushort_t* Bs = ldsB + (size_t)(R & 3) * 8192;

  bf16x8 ah[4], al[4], bh[2], bl[2];
#pragma unroll
  for (int mf = 0; mf < 4; ++mf) {
    int row = wm * 128 + mf * 32 + l32;
    int sw = (row >> 1) & 3;
    ah[mf] = *(const bf16x8*)(As + row * 32 + ((lh ^ sw) * 8));
    al[mf] = *(const bf16x8*)(As + row * 32 + (((2 + lh) ^ sw) * 8));
  }
#pragma unroll
  for (int nf = 0; nf < 2; ++nf) {
    int row = wn * 64 + nf * 32 + l32;
    int sw = (row >> 1) & 3;
    bh[nf] = *(const bf16x8*)(Bs + row * 32 + ((lh ^ sw) * 8));
    bl[nf] = *(const bf16x8*)(Bs + row * 32 + (((2 + lh) ^ sw) * 8));
  }

  if constexpr (ISSUE) stage_pair(R + 3, tid, xpl, wpl, rm0, cn0, ldsA, ldsB);

  __builtin_amdgcn_s_setprio(1);
#pragma unroll
  for (int mf = 0; mf < 4; ++mf)
#pragma unroll
    for (int nf = 0; nf < 2; ++nf) {
      acc[mf][nf] = __builtin_amdgcn_mfma_f32_32x32x16_bf16(ah[mf], bh[nf], acc[mf][nf], 0, 0, 0);
      acc[mf][nf] = __builtin_amdgcn_mfma_f32_32x32x16_bf16(ah[mf], bl[nf], acc[mf][nf], 0, 0, 0);
      acc[mf][nf] = __builtin_amdgcn_mfma_f32_32x32x16_bf16(al[mf], bh[nf], acc[mf][nf], 0, 0, 0);
    }
  __builtin_amdgcn_s_setprio(0);
}

__global__ __launch_bounds__(512, 2) void gemm_mfma2(
    const ushort_t* __restrict__ xpl, const ushort_t* __restrict__ wpl,
    float* __restrict__ S) {
  __shared__ alignas(16) ushort_t lds[65536];  // A ring 64 KB | B ring 64 KB
  ushort_t* ldsA = lds;
  ushort_t* ldsB = lds + 32768;

  const int tid = threadIdx.x;
  const int wid = tid >> 6, lane = tid & 63;
  const int l32 = lane & 31, lh = lane >> 5;
  const int wm = wid >> 2, wn = wid & 3;   // 2M x 4N waves

  // XCD-chunked bijective swizzle: 2048 wgs, each XCD owns 32 M-tiles x 8 N-tiles
  int wg = blockIdx.x;
  int xcd = wg & 7, idx = wg >> 3;         // idx 0..255
  const int mt = xcd * 32 + (idx >> 3);
  const int nt = idx & 7;
  const long rm0 = (long)mt * 256;
  const int cn0 = nt * 256;

  f32x16 acc[4][2] = {};

  // prologue: prefill k-halves 0..2 (12 loads/thread)
#pragma unroll
  for (int j = 0; j < 3; ++j)
    stage_pair(j, tid, xpl, wpl, rm0, cn0, ldsA, ldsB);

  // 32 regions (16 K-tiles x 2 k-steps)
#pragma unroll
  for (int t = 0; t < 14; ++t) {
    region_step<8, true>(2 * t,     tid, l32, lh, wm, wn, xpl, wpl, rm0, cn0, ldsA, ldsB, acc);
    region_step<8, true>(2 * t + 1, tid, l32, lh, wm, wn, xpl, wpl, rm0, cn0, ldsA, ldsB, acc);
  }
  region_step<8, true >(28, tid, l32, lh, wm, wn, xpl, wpl, rm0, cn0, ldsA, ldsB, acc);
  region_step<8, false>(29, tid, l32, lh, wm, wn, xpl, wpl, rm0, cn0, ldsA, ldsB, acc);
  region_step<4, false>(30, tid, l32, lh, wm, wn, xpl, wpl, rm0, cn0, ldsA, ldsB, acc);
  region_step<0, false>(31, tid, l32, lh, wm, wn, xpl, wpl, rm0, cn0, ldsA, ldsB, acc);

  // epilogue: C/D layout col=lane&31, row=(reg&3)+8*(reg>>2)+4*(lane>>5)
#pragma unroll
  for (int mf = 0; mf < 4; ++mf)
#pragma unroll
    for (int nf = 0; nf < 2; ++nf) {
      int col = cn0 + wn * 64 + nf * 32 + l32;
      if (col < MEM) {
        long rbase = rm0 + wm * 128 + mf * 32 + 4 * lh;
#pragma unroll
        for (int r = 0; r < 16; ++r) {
          long row = rbase + (r & 3) + 8 * (r >> 2);
          S[row * MEM + col] = acc[mf][nf][r];
        }
      }
    }
}

// ------------------------------------------------------------------
// Fallback fp32 GEMM (used only if ws too small)
// ------------------------------------------------------------------
#define BK 32
__global__ __launch_bounds__(256) void gemm_scores(
    const float* __restrict__ x, const float* __restrict__ Wt,
    float* __restrict__ S) {
  __shared__ float xs[BK][129];
  __shared__ float ws[BK][129];
  const int tid = threadIdx.x;
  const int rm0 = blockIdx.x * 128;
  const int cn0 = blockIdx.y * 128;
  const int tx = tid & 15, ty = tid >> 4;
  const int sr = tid >> 3, kq = tid & 7;
  float acc[8][8];
#pragma unroll
  for (int i = 0; i < 8; ++i)
#pragma unroll
    for (int j = 0; j < 8; ++j) acc[i][j] = 0.f;
  for (int k0 = 0; k0 < FEA; k0 += BK) {
#pragma unroll
    for (int b = 0; b < 4; ++b) {
      const int row = sr + 32 * b;
      float4 v = *(const float4*)(x + (size_t)(rm0 + row) * FEA + k0 + kq * 4);
      xs[kq * 4 + 0][row] = v.x; xs[kq * 4 + 1][row] = v.y;
      xs[kq * 4 + 2][row] = v.z; xs[kq * 4 + 3][row] = v.w;
      int wr = cn0 + row; wr = (wr < MEM) ? wr : (MEM - 1);
      float4 u = *(const float4*)(Wt + (size_t)wr * FEA + k0 + kq * 4);
      ws[kq * 4 + 0][row] = u.x; ws[kq * 4 + 1][row] = u.y;
      ws[kq * 4 + 2][row] = u.z; ws[kq * 4 + 3][row] = u.w;
    }
    __syncthreads();
#pragma unroll 8
    for (int k = 0; k < BK; ++k) {
      float a[8], bb[8];
      float4 t0 = *(const float4*)&xs[k][4 * ty];
      float4 t1 = *(const float4*)&xs[k][64 + 4 * ty];
      a[0] = t0.x; a[1] = t0.y; a[2] = t0.z; a[3] = t0.w;
      a[4] = t1.x; a[5] = t1.y; a[6] = t1.z; a[7] = t1.w;
      float4 u0 = *(const float4*)&ws[k][4 * tx];
      float4 u1 = *(const float4*)&ws[k][64 + 4 * tx];
      bb[0] = u0.x; bb[1] = u0.y; bb[2] = u0.z; bb[3] = u0.w;
      bb[4] = u1.x; bb[5] = u1.y; bb[6] = u1.z; bb[7] = u1.w;
#pragma unroll
      for (int i = 0; i < 8; ++i)
#pragma unroll
        for (int j = 0; j < 8; ++j)
          acc[i][j] = fmaf(a[i], bb[j], acc[i][j]);
    }
    __syncthreads();
  }
#pragma unroll
  for (int i = 0; i < 8; ++i) {
    const int row = rm0 + ((i < 4) ? (4 * ty + i) : (64 + 4 * ty + (i - 4)));
    const int c0 = cn0 + 4 * tx;
    const int c1 = cn0 + 64 + 4 * tx;
    if (c0 < MEM) {
      float4 v; v.x = acc[i][0]; v.y = acc[i][1]; v.z = acc[i][2]; v.w = acc[i][3];
      *(float4*)(S + (size_t)row * MEM + c0) = v;
    }
    if (c1 < MEM) {
      float4 v; v.x = acc[i][4]; v.y = acc[i][5]; v.z = acc[i][6]; v.w = acc[i][7];
      *(float4*)(S + (size_t)row * MEM + c1) = v;
    }
  }
}

// ------------------------------------------------------------------
// K2: softmax -> hard shrink -> renorm -> write att + sparse out
// ------------------------------------------------------------------
__global__ __launch_bounds__(512) void softmax_shrink_out(
    const float* __restrict__ Wt, float* __restrict__ out,
    float* __restrict__ att /* raw scores on entry */) {
  __shared__ float sl[8 * MEM];
  const int tid = threadIdx.x;
  const int r0 = blockIdx.x * 8;
  {
    const float* Sblk = att + (size_t)r0 * MEM;
#pragma unroll
    for (int jj = 0; jj < 8; ++jj) {
      int q = tid + 512 * jj;
      if (q < (8 * MEM) / 4) {
        float4 v = *(const float4*)(Sblk + 4 * q);
        *(float4*)&sl[4 * q] = v;
      }
    }
  }
  __syncthreads();
  const int w = tid >> 6;
  const int l = tid & 63;
  float* row_lds = &sl[w * MEM];
  const int grow = r0 + w;

  float m = -INFINITY;
  for (int j = 0; j < 32; ++j) {
    int c = l + 64 * j;
    if (c < MEM) m = fmaxf(m, row_lds[c]);
  }
#pragma unroll
  for (int off = 32; off; off >>= 1) m = fmaxf(m, __shfl_xor(m, off));

  float s = 0.f;
  for (int j = 0; j < 32; ++j) {
    int c = l + 64 * j;
    if (c < MEM) {
      float e = expf(row_lds[c] - m);
      row_lds[c] = e;
      s += e;
    }
  }
#pragma unroll
  for (int off = 32; off; off >>= 1) s += __shfl_xor(s, off);

  float qs = 0.f;
  for (int j = 0; j < 32; ++j) {
    int c = l + 64 * j;
    if (c < MEM) {
      float p = row_lds[c] / s;
      float d = p - LAMBDA;
      float q = fmaxf(d, 0.f) * p / (fabsf(d) + EPS);
      row_lds[c] = q;
      qs += q;
    }
  }
#pragma unroll
  for (int off = 32; off; off >>= 1) qs += __shfl_xor(qs, off);
  const float denom = fmaxf(qs, EPS);

  float4 oa0 = {0.f, 0.f, 0.f, 0.f};
  float4 oa1 = {0.f, 0.f, 0.f, 0.f};
  for (int j = 0; j < 32; ++j) {
    int c = l + 64 * j;
    float a = 0.f;
    if (c < MEM) {
      a = row_lds[c] / denom;
      att[(size_t)grow * MEM + c] = a;
    }
    unsigned long long msk = __ballot(a > 0.f);
    while (msk) {
      int b = __ffsll(msk) - 1;
      msk &= msk - 1;
      float av = __shfl(a, b);
      int cc = b + 64 * j;
      const float* wp = Wt + (size_t)cc * FEA;
      float4 w0 = *(const float4*)(wp + 4 * l);
      float4 w1 = *(const float4*)(wp + 256 + 4 * l);
      oa0.x = fmaf(av, w0.x, oa0.x); oa0.y = fmaf(av, w0.y, oa0.y);
      oa0.z = fmaf(av, w0.z, oa0.z); oa0.w = fmaf(av, w0.w, oa0.w);
      oa1.x = fmaf(av, w1.x, oa1.x); oa1.y = fmaf(av, w1.y, oa1.y);
      oa1.z = fmaf(av, w1.z, oa1.z); oa1.w = fmaf(av, w1.w, oa1.w);
    }
  }
  float* op = out + (size_t)grow * FEA;
  *(float4*)(op + 4 * l) = oa0;
  *(float4*)(op + 256 + 4 * l) = oa1;
}

// ------------------------------------------------------------------
extern "C" void kernel_launch(void* const* d_in, const int* in_sizes, int n_in,
                              void* d_out, int out_size, void* d_ws, size_t ws_size,
                              hipStream_t stream) {
  (void)in_sizes; (void)n_in; (void)out_size;
  const float* x = (const float*)d_in[0];
  const float* W = (const float*)d_in[1];
  float* out = (float*)d_out;
  float* att = (float*)d_out + (size_t)NROWS * FEA;

  const size_t w_need = (size_t)PLW * 2 * sizeof(ushort_t);  // 4 MB
  if (ws_size >= w_need) {
    ushort_t* xpl = (ushort_t*)d_out;  // out region: exactly fits 2 x-planes
    ushort_t* wpl = (ushort_t*)d_ws;
    split_x<<<2048, 256, 0, stream>>>(x, xpl);
    split_w<<<(int)(PLW / 4 / 256), 256, 0, stream>>>(W, wpl);
    gemm_mfma2<<<2048, 512, 0, stream>>>(xpl, wpl, att);
  } else {
    dim3 g1(NROWS / 128, (MEM + 127) / 128);
    gemm_scores<<<g1, 256, 0, stream>>>(x, W, att);
  }
  softmax_shrink_out<<<NROWS / 8, 512, 0, stream>>>(W, out, att);
}

// Round 4
// 786.732 us; speedup vs baseline: 2.3891x; 1.0051x over previous
//
#include <hip/hip_runtime.h>

#define NROWS 65536
#define FEA   512
#define MEM   2000
#define MEMP  2048
#define LAMBDA 0.0025f
#define EPS    1e-12f

#define PLX ((long)NROWS * FEA)   // elements per x plane
#define PLW ((long)MEMP * FEA)    // elements per W plane

typedef unsigned short ushort_t;
typedef __attribute__((ext_vector_type(8))) short bf16x8;
typedef __attribute__((ext_vector_type(16))) float f32x16;

// ---------- bf16 split helpers (RNE) ----------
__device__ inline ushort_t f2bf(float f) {
  unsigned int u = __float_as_uint(f);
  unsigned int r = (u + 0x7FFFu + ((u >> 16) & 1u)) >> 16;
  return (ushort_t)r;
}
__device__ inline float bf2f(ushort_t h) {
  return __uint_as_float(((unsigned int)h) << 16);
}

__device__ inline void gload_lds16(const void* g, void* l) {
  __builtin_amdgcn_global_load_lds(
      (const __attribute__((address_space(1))) unsigned int*)g,
      (__attribute__((address_space(3))) unsigned int*)l, 16, 0, 0);
}

// ------------------------------------------------------------------
// K0a: split x (fp32) -> xh, xl bf16 planes (stored in out region)
// ------------------------------------------------------------------
__global__ __launch_bounds__(256) void split_x(const float* __restrict__ x,
                                               ushort_t* __restrict__ xpl) {
  const long n4 = PLX / 4;
  long i = (long)blockIdx.x * 256 + threadIdx.x;
  const long stride = (long)gridDim.x * 256;
  for (; i < n4; i += stride) {
    float4 v = ((const float4*)x)[i];
    float f[4] = {v.x, v.y, v.z, v.w};
    ushort_t hh[4], ll[4];
#pragma unroll
    for (int j = 0; j < 4; ++j) {
      hh[j] = f2bf(f[j]);
      ll[j] = f2bf(f[j] - bf2f(hh[j]));
    }
    ushort4 h; h.x = hh[0]; h.y = hh[1]; h.z = hh[2]; h.w = hh[3];
    ushort4 l; l.x = ll[0]; l.y = ll[1]; l.z = ll[2]; l.w = ll[3];
    ((ushort4*)xpl)[i] = h;
    ((ushort4*)(xpl + PLX))[i] = l;
  }
}

// ------------------------------------------------------------------
// K0b: split W -> wh, wl planes, padded to 2048 rows (zeros)
// ------------------------------------------------------------------
__global__ __launch_bounds__(256) void split_w(const float* __restrict__ W,
                                               ushort_t* __restrict__ wpl) {
  long i = (long)blockIdx.x * 256 + threadIdx.x;
  if (i >= PLW / 4) return;
  long row = i / (FEA / 4);
  ushort4 h = {0, 0, 0, 0}, l = {0, 0, 0, 0};
  if (row < MEM) {
    float4 v = ((const float4*)W)[i];
    float f[4] = {v.x, v.y, v.z, v.w};
    ushort_t hh[4], ll[4];
#pragma unroll
    for (int j = 0; j < 4; ++j) {
      hh[j] = f2bf(f[j]);
      ll[j] = f2bf(f[j] - bf2f(hh[j]));
    }
    h.x = hh[0]; h.y = hh[1]; h.z = hh[2]; h.w = hh[3];
    l.x = ll[0]; l.y = ll[1]; l.z = ll[2]; l.w = ll[3];
  }
  ((ushort4*)wpl)[i] = h;
  ((ushort4*)(wpl + PLW))[i] = l;
}

// ------------------------------------------------------------------
// K1: S = x @ W^T, split-bf16 (3 products), 256x256 tile, BK=32.
// Two-phase regions (template port): ds_reads BEFORE barrier, MFMA
// after; counted vmcnt(8); setprio around MFMA clusters.
// Slot: [256 rows][2 planes][16 k] bf16 = 64 B/row = 16 KB; ring of 4.
// Chunk swizzle: phys = c ^ ((row>>1)&3).
// ------------------------------------------------------------------
__device__ __forceinline__ void stageA(int j, int tid,
                                       const ushort_t* __restrict__ xpl,
                                       long rm0, ushort_t* ldsA) {
  ushort_t* dA = ldsA + (size_t)(j & 3) * 8192;
#pragma unroll
  for (int i = 0; i < 2; ++i) {
    int id = i * 512 + tid;
    int row = id >> 2;
    int c = (id & 3) ^ ((row >> 1) & 3);
    long goff = (long)(c >> 1) * PLX + (rm0 + row) * FEA + j * 16 + (c & 1) * 8;
    gload_lds16(xpl + goff, dA + id * 8);
  }
}
__device__ __forceinline__ void stageB(int j, int tid,
                                       const ushort_t* __restrict__ wpl,
                                       int cn0, ushort_t* ldsB) {
  ushort_t* dB = ldsB + (size_t)(j & 3) * 8192;
#pragma unroll
  for (int i = 0; i < 2; ++i) {
    int id = i * 512 + tid;
    int row = id >> 2;
    int c = (id & 3) ^ ((row >> 1) & 3);
    long goff = (long)(c >> 1) * PLW + (long)(cn0 + row) * FEA + j * 16 + (c & 1) * 8;
    gload_lds16(wpl + goff, dB + id * 8);
  }
}

template <int SLOT, bool ISSUE, int VM>
__device__ __forceinline__ void region(
    int j3, int tid, int l32, int lh, int wm, int wn,
    const ushort_t* __restrict__ xpl, const ushort_t* __restrict__ wpl,
    long rm0, int cn0, ushort_t* ldsA, ushort_t* ldsB, f32x16 (&acc)[4][2]) {
  const ushort_t* As = ldsA + SLOT * 8192;
  const ushort_t* Bs = ldsB + SLOT * 8192;

  // ================= phase A =================
  bf16x8 ah0, al0, ah1, al1, bh0, bl0, bh1, bl1;
  {
    int r = wm * 128 + l32;       int sw = (r >> 1) & 3;
    ah0 = *(const bf16x8*)(As + r * 32 + ((lh ^ sw) * 8));
    al0 = *(const bf16x8*)(As + r * 32 + (((2 + lh) ^ sw) * 8));
  }
  {
    int r = wm * 128 + 32 + l32;  int sw = (r >> 1) & 3;
    ah1 = *(const bf16x8*)(As + r * 32 + ((lh ^ sw) * 8));
    al1 = *(const bf16x8*)(As + r * 32 + (((2 + lh) ^ sw) * 8));
  }
  {
    int r = wn * 64 + l32;        int sw = (r >> 1) & 3;
    bh0 = *(const bf16x8*)(Bs + r * 32 + ((lh ^ sw) * 8));
    bl0 = *(const bf16x8*)(Bs + r * 32 + (((2 + lh) ^ sw) * 8));
  }
  {
    int r = wn * 64 + 32 + l32;   int sw = (r >> 1) & 3;
    bh1 = *(const bf16x8*)(Bs + r * 32 + ((lh ^ sw) * 8));
    bl1 = *(const bf16x8*)(Bs + r * 32 + (((2 + lh) ^ sw) * 8));
  }
  if constexpr (ISSUE) stageA(j3, tid, xpl, rm0, ldsA);
  asm volatile("s_barrier" ::: "memory");
  __builtin_amdgcn_sched_barrier(0);
  __builtin_amdgcn_s_setprio(1);
  acc[0][0] = __builtin_amdgcn_mfma_f32_32x32x16_bf16(ah0, bh0, acc[0][0], 0, 0, 0);
  acc[0][0] = __builtin_amdgcn_mfma_f32_32x32x16_bf16(ah0, bl0, acc[0][0], 0, 0, 0);
  acc[0][0] = __builtin_amdgcn_mfma_f32_32x32x16_bf16(al0, bh0, acc[0][0], 0, 0, 0);
  acc[0][1] = __builtin_amdgcn_mfma_f32_32x32x16_bf16(ah0, bh1, acc[0][1], 0, 0, 0);
  acc[0][1] = __builtin_amdgcn_mfma_f32_32x32x16_bf16(ah0, bl1, acc[0][1], 0, 0, 0);
  acc[0][1] = __builtin_amdgcn_mfma_f32_32x32x16_bf16(al0, bh1, acc[0][1], 0, 0, 0);
  acc[1][0] = __builtin_amdgcn_mfma_f32_32x32x16_bf16(ah1, bh0, acc[1][0], 0, 0, 0);
  acc[1][0] = __builtin_amdgcn_mfma_f32_32x32x16_bf16(ah1, bl0, acc[1][0], 0, 0, 0);
  acc[1][0] = __builtin_amdgcn_mfma_f32_32x32x16_bf16(al1, bh0, acc[1][0], 0, 0, 0);
  acc[1][1] = __builtin_amdgcn_mfma_f32_32x32x16_bf16(ah1, bh1, acc[1][1], 0, 0, 0);
  acc[1][1] = __builtin_amdgcn_mfma_f32_32x32x16_bf16(ah1, bl1, acc[1][1], 0, 0, 0);
  acc[1][1] = __builtin_amdgcn_mfma_f32_32x32x16_bf16(al1, bh1, acc[1][1], 0, 0, 0);
  __builtin_amdgcn_s_setprio(0);
  asm volatile("s_barrier" ::: "memory");

  // ================= phase B =================
  bf16x8 ah2, al2, ah3, al3;
  {
    int r = wm * 128 + 64 + l32;  int sw = (r >> 1) & 3;
    ah2 = *(const bf16x8*)(As + r * 32 + ((lh ^ sw) * 8));
    al2 = *(const bf16x8*)(As + r * 32 + (((2 + lh) ^ sw) * 8));
  }
  {
    int r = wm * 128 + 96 + l32;  int sw = (r >> 1) & 3;
    ah3 = *(const bf16x8*)(As + r * 32 + ((lh ^ sw) * 8));
    al3 = *(const bf16x8*)(As + r * 32 + (((2 + lh) ^ sw) * 8));
  }
  if constexpr (ISSUE) stageB(j3, tid, wpl, cn0, ldsB);
  asm volatile("s_barrier" ::: "memory");
  __builtin_amdgcn_sched_barrier(0);
  __builtin_amdgcn_s_setprio(1);
  acc[2][0] = __builtin_amdgcn_mfma_f32_32x32x16_bf16(ah2, bh0, acc[2][0], 0, 0, 0);
  acc[2][0] = __builtin_amdgcn_mfma_f32_32x32x16_bf16(ah2, bl0, acc[2][0], 0, 0, 0);
  acc[2][0] = __builtin_amdgcn_mfma_f32_32x32x16_bf16(al2, bh0, acc[2][0], 0, 0, 0);
  acc[2][1] = __builtin_amdgcn_mfma_f32_32x32x16_bf16(ah2, bh1, acc[2][1], 0, 0, 0);
  acc[2][1] = __builtin_amdgcn_mfma_f32_32x32x16_bf16(ah2, bl1, acc[2][1], 0, 0, 0);
  acc[2][1] = __builtin_amdgcn_mfma_f32_32x32x16_bf16(al2, bh1, acc[2][1], 0, 0, 0);
  acc[3][0] = __builtin_amdgcn_mfma_f32_32x32x16_bf16(ah3, bh0, acc[3][0], 0, 0, 0);
  acc[3][0] = __builtin_amdgcn_mfma_f32_32x32x16_bf16(ah3, bl0, acc[3][0], 0, 0, 0);
  acc[3][0] = __builtin_amdgcn_mfma_f32_32x32x16_bf16(al3, bh0, acc[3][0], 0, 0, 0);
  acc[3][1] = __builtin_amdgcn_mfma_f32_32x32x16_bf16(ah3, bh1, acc[3][1], 0, 0, 0);
  acc[3][1] = __builtin_amdgcn_mfma_f32_32x32x16_bf16(ah3, bl1, acc[3][1], 0, 0, 0);
  acc[3][1] = __builtin_amdgcn_mfma_f32_32x32x16_bf16(al3, bh1, acc[3][1], 0, 0, 0);
  __builtin_amdgcn_s_setprio(0);
  if constexpr (VM == 8)      asm volatile("s_waitcnt vmcnt(8)" ::: "memory");
  else if constexpr (VM == 4) asm volatile("s_waitcnt vmcnt(4)" ::: "memory");
  else if constexpr (VM == 0) asm volatile("s_waitcnt vmcnt(0)" ::: "memory");
  if constexpr (VM >= 0) asm volatile("s_barrier" ::: "memory");
}

__global__ __launch_bounds__(512, 2) void gemm_mfma2(
    const ushort_t* __restrict__ xpl, const ushort_t* __restrict__ wpl,
    float* __restrict__ S) {
  __shared__ alignas(16) ushort_t lds[65536];  // A ring 64 KB | B ring 64 KB
  ushort_t* ldsA = lds;
  ushort_t* ldsB = lds + 32768;

  const int tid = threadIdx.x;
  const int wid = tid >> 6, lane = tid & 63;
  const int l32 = lane & 31, lh = lane >> 5;
  const int wm = wid >> 2, wn = wid & 3;   // 2M x 4N waves

  // XCD-chunked bijective swizzle: 2048 wgs, each XCD owns 32 M-tiles x 8 N-tiles
  int wg = blockIdx.x;
  int xcd = wg & 7, idx = wg >> 3;
  const int mt = xcd * 32 + (idx >> 3);
  const int nt = idx & 7;
  const long rm0 = (long)mt * 256;
  const int cn0 = nt * 256;

  f32x16 acc[4][2] = {};

  // prologue: prefill k-halves 0..2 (A,B interleaved -> 12 loads/thread)
  stageA(0, tid, xpl, rm0, ldsA); stageB(0, tid, wpl, cn0, ldsB);
  stageA(1, tid, xpl, rm0, ldsA); stageB(1, tid, wpl, cn0, ldsB);
  stageA(2, tid, xpl, rm0, ldsA); stageB(2, tid, wpl, cn0, ldsB);
  asm volatile("s_waitcnt vmcnt(8)" ::: "memory");
  asm volatile("s_barrier" ::: "memory");

  // 32 regions (16 K-tiles x 2 k-halves); regions 0..27 in unroll-4 loop
  for (int t = 0; t < 7; ++t) {
    region<0, true, 8>(4 * t + 3, tid, l32, lh, wm, wn, xpl, wpl, rm0, cn0, ldsA, ldsB, acc);
    region<1, true, 8>(4 * t + 4, tid, l32, lh, wm, wn, xpl, wpl, rm0, cn0, ldsA, ldsB, acc);
    region<2, true, 8>(4 * t + 5, tid, l32, lh, wm, wn, xpl, wpl, rm0, cn0, ldsA, ldsB, acc);
    region<3, true, 8>(4 * t + 6, tid, l32, lh, wm, wn, xpl, wpl, rm0, cn0, ldsA, ldsB, acc);
  }
  region<0, true,  8>(31, tid, l32, lh, wm, wn, xpl, wpl, rm0, cn0, ldsA, ldsB, acc);  // R=28
  region<1, false, 4>(0,  tid, l32, lh, wm, wn, xpl, wpl, rm0, cn0, ldsA, ldsB, acc);  // R=29
  region<2, false, 0>(0,  tid, l32, lh, wm, wn, xpl, wpl, rm0, cn0, ldsA, ldsB, acc);  // R=30
  region<3, false, -1>(0, tid, l32, lh, wm, wn, xpl, wpl, rm0, cn0, ldsA, ldsB, acc);  // R=31

  // epilogue: C/D layout col=lane&31, row=(reg&3)+8*(reg>>2)+4*(lane>>5)
#pragma unroll
  for (int mf = 0; mf < 4; ++mf)
#pragma unroll
    for (int nf = 0; nf < 2; ++nf) {
      int col = cn0 + wn * 64 + nf * 32 + l32;
      if (col < MEM) {
        long rbase = rm0 + wm * 128 + mf * 32 + 4 * lh;
#pragma unroll
        for (int r = 0; r < 16; ++r) {
          long row = rbase + (r & 3) + 8 * (r >> 2);
          S[row * MEM + col] = acc[mf][nf][r];
        }
      }
    }
}

// ------------------------------------------------------------------
// Fallback fp32 GEMM (used only if ws too small)
// ------------------------------------------------------------------
#define BK 32
__global__ __launch_bounds__(256) void gemm_scores(
    const float* __restrict__ x, const float* __restrict__ Wt,
    float* __restrict__ S) {
  __shared__ float xs[BK][129];
  __shared__ float ws[BK][129];
  const int tid = threadIdx.x;
  const int rm0 = blockIdx.x * 128;
  const int cn0 = blockIdx.y * 128;
  const int tx = tid & 15, ty = tid >> 4;
  const int sr = tid >> 3, kq = tid & 7;
  float acc[8][8];
#pragma unroll
  for (int i = 0; i < 8; ++i)
#pragma unroll
    for (int j = 0; j < 8; ++j) acc[i][j] = 0.f;
  for (int k0 = 0; k0 < FEA; k0 += BK) {
#pragma unroll
    for (int b = 0; b < 4; ++b) {
      const int row = sr + 32 * b;
      float4 v = *(const float4*)(x + (size_t)(rm0 + row) * FEA + k0 + kq * 4);
      xs[kq * 4 + 0][row] = v.x; xs[kq * 4 + 1][row] = v.y;
      xs[kq * 4 + 2][row] = v.z; xs[kq * 4 + 3][row] = v.w;
      int wr = cn0 + row; wr = (wr < MEM) ? wr : (MEM - 1);
      float4 u = *(const float4*)(Wt + (size_t)wr * FEA + k0 + kq * 4);
      ws[kq * 4 + 0][row] = u.x; ws[kq * 4 + 1][row] = u.y;
      ws[kq * 4 + 2][row] = u.z; ws[kq * 4 + 3][row] = u.w;
    }
    __syncthreads();
#pragma unroll 8
    for (int k = 0; k < BK; ++k) {
      float a[8], bb[8];
      float4 t0 = *(const float4*)&xs[k][4 * ty];
      float4 t1 = *(const float4*)&xs[k][64 + 4 * ty];
      a[0] = t0.x; a[1] = t0.y; a[2] = t0.z; a[3] = t0.w;
      a[4] = t1.x; a[5] = t1.y; a[6] = t1.z; a[7] = t1.w;
      float4 u0 = *(const float4*)&ws[k][4 * tx];
      float4 u1 = *(const float4*)&ws[k][64 + 4 * tx];
      bb[0] = u0.x; bb[1] = u0.y; bb[2] = u0.z; bb[3] = u0.w;
      bb[4] = u1.x; bb[5] = u1.y; bb[6] = u1.z; bb[7] = u1.w;
#pragma unroll
      for (int i = 0; i < 8; ++i)
#pragma unroll
        for (int j = 0; j < 8; ++j)
          acc[i][j] = fmaf(a[i], bb[j], acc[i][j]);
    }
    __syncthreads();
  }
#pragma unroll
  for (int i = 0; i < 8; ++i) {
    const int row = rm0 + ((i < 4) ? (4 * ty + i) : (64 + 4 * ty + (i - 4)));
    const int c0 = cn0 + 4 * tx;
    const int c1 = cn0 + 64 + 4 * tx;
    if (c0 < MEM) {
      float4 v; v.x = acc[i][0]; v.y = acc[i][1]; v.z = acc[i][2]; v.w = acc[i][3];
      *(float4*)(S + (size_t)row * MEM + c0) = v;
    }
    if (c1 < MEM) {
      float4 v; v.x = acc[i][4]; v.y = acc[i][5]; v.z = acc[i][6]; v.w = acc[i][7];
      *(float4*)(S + (size_t)row * MEM + c1) = v;
    }
  }
}

// ------------------------------------------------------------------
// K2: softmax -> hard shrink -> renorm -> write att + sparse out
// ------------------------------------------------------------------
__global__ __launch_bounds__(512) void softmax_shrink_out(
    const float* __restrict__ Wt, float* __restrict__ out,
    float* __restrict__ att /* raw scores on entry */) {
  __shared__ float sl[8 * MEM];
  const int tid = threadIdx.x;
  const int r0 = blockIdx.x * 8;
  {
    const float* Sblk = att + (size_t)r0 * MEM;
#pragma unroll
    for (int jj = 0; jj < 8; ++jj) {
      int q = tid + 512 * jj;
      if (q < (8 * MEM) / 4) {
        float4 v = *(const float4*)(Sblk + 4 * q);
        *(float4*)&sl[4 * q] = v;
      }
    }
  }
  __syncthreads();
  const int w = tid >> 6;
  const int l = tid & 63;
  float* row_lds = &sl[w * MEM];
  const int grow = r0 + w;

  float m = -INFINITY;
  for (int j = 0; j < 32; ++j) {
    int c = l + 64 * j;
    if (c < MEM) m = fmaxf(m, row_lds[c]);
  }
#pragma unroll
  for (int off = 32; off; off >>= 1) m = fmaxf(m, __shfl_xor(m, off));

  float s = 0.f;
  for (int j = 0; j < 32; ++j) {
    int c = l + 64 * j;
    if (c < MEM) {
      float e = expf(row_lds[c] - m);
      row_lds[c] = e;
      s += e;
    }
  }
#pragma unroll
  for (int off = 32; off; off >>= 1) s += __shfl_xor(s, off);

  float qs = 0.f;
  for (int j = 0; j < 32; ++j) {
    int c = l + 64 * j;
    if (c < MEM) {
      float p = row_lds[c] / s;
      float d = p - LAMBDA;
      float q = fmaxf(d, 0.f) * p / (fabsf(d) + EPS);
      row_lds[c] = q;
      qs += q;
    }
  }
#pragma unroll
  for (int off = 32; off; off >>= 1) qs += __shfl_xor(qs, off);
  const float denom = fmaxf(qs, EPS);

  float4 oa0 = {0.f, 0.f, 0.f, 0.f};
  float4 oa1 = {0.f, 0.f, 0.f, 0.f};
  for (int j = 0; j < 32; ++j) {
    int c = l + 64 * j;
    float a = 0.f;
    if (c < MEM) {
      a = row_lds[c] / denom;
      att[(size_t)grow * MEM + c] = a;
    }
    unsigned long long msk = __ballot(a > 0.f);
    while (msk) {
      int b = __ffsll(msk) - 1;
      msk &= msk - 1;
      float av = __shfl(a, b);
      int cc = b + 64 * j;
      const float* wp = Wt + (size_t)cc * FEA;
      float4 w0 = *(const float4*)(wp + 4 * l);
      float4 w1 = *(const float4*)(wp + 256 + 4 * l);
      oa0.x = fmaf(av, w0.x, oa0.x); oa0.y = fmaf(av, w0.y, oa0.y);
      oa0.z = fmaf(av, w0.z, oa0.z); oa0.w = fmaf(av, w0.w, oa0.w);
      oa1.x = fmaf(av, w1.x, oa1.x); oa1.y = fmaf(av, w1.y, oa1.y);
      oa1.z = fmaf(av, w1.z, oa1.z); oa1.w = fmaf(av, w1.w, oa1.w);
    }
  }
  float* op = out + (size_t)grow * FEA;
  *(float4*)(op + 4 * l) = oa0;
  *(float4*)(op + 256 + 4 * l) = oa1;
}

// ------------------------------------------------------------------
extern "C" void kernel_launch(void* const* d_in, const int* in_sizes, int n_in,
                              void* d_out, int out_size, void* d_ws, size_t ws_size,
                              hipStream_t stream) {
  (void)in_sizes; (void)n_in; (void)out_size;
  const float* x = (const float*)d_in[0];
  const float* W = (const float*)d_in[1];
  float* out = (float*)d_out;
  float* att = (float*)d_out + (size_t)NROWS * FEA;

  const size_t w_need = (size_t)PLW * 2 * sizeof(ushort_t);  // 4 MB
  if (ws_size >= w_need) {
    ushort_t* xpl = (ushort_t*)d_out;  // out region: exactly fits 2 x-planes
    ushort_t* wpl = (ushort_t*)d_ws;
    split_x<<<2048, 256, 0, stream>>>(x, xpl);
    split_w<<<(int)(PLW / 4 / 256), 256, 0, stream>>>(W, wpl);
    gemm_mfma2<<<2048, 512, 0, stream>>>(xpl, wpl, att);
  } else {
    dim3 g1(NROWS / 128, (MEM + 127) / 128);
    gemm_scores<<<g1, 256, 0, stream>>>(x, W, att);
  }
  softmax_shrink_out<<<NROWS / 8, 512, 0, stream>>>(W, out, att);
}